// Round 11
// baseline (18073.203 us; speedup 1.0000x reference)
//
#include <hip/hip_runtime.h>
#include <math.h>

#define TT 2048
#define II 64
#define HH 512
#define LL 5
#define RING 64
#define BPL 32                 // blocks per layer
#define NBLK 256               // 1 block/CU => exactly 32 blocks/XCD
#define CW 8                   // compute waves per block
#define JPW 2                  // outputs per compute wave
#define SPIN_LIMIT 2000000L
#define BARRIER_SPIN 20000000L

typedef unsigned long long u64;
typedef unsigned u32;

__device__ __forceinline__ float wave_sum(float v) {
#pragma unroll
  for (int m = 32; m > 0; m >>= 1) v += __shfl_xor(v, m, 64);
  return v;
}

__device__ __forceinline__ float wave_max(float v) {
#pragma unroll
  for (int m = 32; m > 0; m >>= 1) v = fmaxf(v, __shfl_xor(v, m, 64));
  return v;
}

__device__ __forceinline__ float sigmoidf_(float v) {
  return 1.0f / (1.0f + expf(-v));
}

// MALL-coherent (agent-scope relaxed) accessors — proven transport (r3..r10)
__device__ __forceinline__ u32 ld4(const u32* p) {
  return __hip_atomic_load((u32*)p, __ATOMIC_RELAXED, __HIP_MEMORY_SCOPE_AGENT);
}
__device__ __forceinline__ void st4(u32* p, u32 v) {
  __hip_atomic_store(p, v, __ATOMIC_RELAXED, __HIP_MEMORY_SCOPE_AGENT);
}
__device__ __forceinline__ u64 ld8(const u64* p) {
  return __hip_atomic_load((u64*)p, __ATOMIC_RELAXED, __HIP_MEMORY_SCOPE_AGENT);
}
__device__ __forceinline__ void st8(u64* p, u64 v) {
  __hip_atomic_store(p, v, __ATOMIC_RELAXED, __HIP_MEMORY_SCOPE_AGENT);
}

// single-target poll (r9-proven 2-deep)
__device__ __forceinline__ float poll_ring(const u64* p, u32 want) {
  u64 a = ld8(p);
  u64 b = ld8(p);
  long sp = 0;
  while ((u32)(a >> 32) != want) {
    a = b;
    b = ld8(p);
    if (++sp > SPIN_LIMIT) { a = ((u64)want << 32); break; }
  }
  return __uint_as_float((u32)a);
}

// fused dual poll: own + prev concurrently (both loads in flight)
__device__ __forceinline__ void poll2(const u64* po, u32 wo, const u64* pp, u32 wp,
                                      float* ro, float* rp) {
  u64 va = ld8(po), vb = ld8(pp);
  bool da = false, db = false;
  long sp = 0;
  for (;;) {
    if (!da) {
      if ((u32)(va >> 32) == wo) { *ro = __uint_as_float((u32)va); da = true; }
      else va = ld8(po);
    }
    if (!db) {
      if ((u32)(vb >> 32) == wp) { *rp = __uint_as_float((u32)vb); db = true; }
      else vb = ld8(pp);
    }
    if (da && db) break;
    if (++sp > SPIN_LIMIT) { if (!da) *ro = 0.0f; if (!db) *rp = 0.0f; break; }
  }
}

__device__ __forceinline__ void wait_ge(u32* p, u32 v) {
  long spins = 0;
  while (ld4(p) < v) {
    if (++spins > BARRIER_SPIN) {
      __hip_atomic_fetch_max(p, v, __ATOMIC_RELAXED, __HIP_MEMORY_SCOPE_AGENT);
      break;
    }
  }
}

__device__ __forceinline__ void grid_barrier(u32* arrive, u32* gen, u32 idx) {
  __syncthreads();
  if (threadIdx.x == 0) {
    __threadfence();  // release
    u32 target = (u32)NBLK * (idx + 1u);
    u32 prev = __hip_atomic_fetch_add(arrive, 1u, __ATOMIC_RELAXED, __HIP_MEMORY_SCOPE_AGENT);
    if (prev + 1u == target) {
      __hip_atomic_store(gen, idx + 1u, __ATOMIC_RELAXED, __HIP_MEMORY_SCOPE_AGENT);
    } else {
      wait_ge(gen, idx + 1u);
    }
    __threadfence();  // acquire
  }
  __syncthreads();
}

extern "C" __global__ void __launch_bounds__(1024)
__attribute__((amdgpu_waves_per_eu(4, 4)))
lstm_pipe(
    const float* __restrict__ x,
    const float* __restrict__ w_ih0, const float* __restrict__ w_hh0,
    const float* __restrict__ b_ih0, const float* __restrict__ b_hh0,
    const float* __restrict__ w_ih, const float* __restrict__ w_hh,
    const float* __restrict__ b_ih, const float* __restrict__ b_hh,
    const float* __restrict__ w_lin, const float* __restrict__ b_lin,
    float* __restrict__ out, float* __restrict__ ws) {
  extern __shared__ float wihs[];   // [16 outputs][4][HH] = 128 KB dynamic
  __shared__ float hbuf[2][HH];     // dbuf: staged own-layer h
  __shared__ float xbuf[2][HH];     // dbuf: staged prev-layer h / x
  __shared__ float sbuf[20];
  __shared__ int s_layer, s_slot;

  // counters (first 4 KB of ws, memset 0): prog[l] at cnt[l*64];
  // garr cnt[320]; ggen cnt[336]; claims[xcd] cnt[352+xcd*16]; flag cnt[448]
  u32* cnt = (u32*)ws;
  u32* garr = cnt + 320;
  u32* ggen = cnt + 336;
  u32* claims = cnt + 352;
  u32* flagp = cnt + 448;

  // tagged h ring: [LL][RING][HH] u64 — (tag=t+1)<<32 | bits(h)
  u64* ring = (u64*)((char*)ws + 4096);
  float* h4 = (float*)(ring + (size_t)LL * RING * HH);   // TT*HH
  float* h4T = h4 + (size_t)TT * HH;                     // HH*TT
  float* scores = h4T + (size_t)HH * TT;                 // TT
  float* pbuf = scores + TT;                             // TT
  float* red = pbuf + TT;                                // 1

  const int b = blockIdx.x;
  const int tid = threadIdx.x;
  const int wv = tid >> 6;
  const int lane = tid & 63;

  // ---- placement: claim (layer, slot) on own XCD (r10-proven, w/ fallback) ----
  if (tid == 0) {
    u32 xcc = 0;
    asm volatile("s_getreg_b32 %0, hwreg(HW_REG_XCC_ID)" : "=s"(xcc));
    xcc &= 7u;
    int layer = -1, slot = 0;
    if (xcc < LL) {
      u32 idx = __hip_atomic_fetch_add(claims + xcc * 16, 1u, __ATOMIC_RELAXED,
                                       __HIP_MEMORY_SCOPE_AGENT);
      if (idx < (u32)BPL) { layer = (int)xcc; slot = (int)idx; }
    }
    s_layer = layer; s_slot = slot;
  }
  grid_barrier(garr, ggen, 0u);
  if (b == 0 && tid == 0) {
    bool ok = true;
    for (int l = 0; l < LL; ++l) ok &= (ld4(claims + l * 16) >= (u32)BPL);
    st4(flagp, ok ? 1u : 2u);
  }
  grid_barrier(garr, ggen, 1u);
  if (tid == 0 && ld4(flagp) == 2u) {  // fallback: fixed mapping
    s_layer = (b < LL * BPL) ? (b / BPL) : -1;
    s_slot = (b < LL * BPL) ? (b % BPL) : 0;
  }
  __syncthreads();
  const int layer = s_layer;
  const int slot = s_slot;

  if (layer >= 0) {
    const bool is_comp = (wv < CW);
    const bool is_last = (layer == LL - 1);
    const int j0 = slot * (CW * JPW) + wv * JPW;  // compute wave outputs j0, j0+1
    u32* prog_l = cnt + layer * 64;
    u32* prog_lp1 = cnt + (layer + 1) * 64;
    u64* myring = ring + (size_t)layer * RING * HH;
    u64* prevring = ring + (size_t)(layer > 0 ? layer - 1 : 0) * RING * HH;

    // ---- weights: whh+bias in regs (compute waves only); wih in LDS ----
    float whh[JPW][4][8], bias[JPW][4];
    if (is_comp) {
      const float* WHH = (layer == 0) ? w_hh0 : (w_hh + (size_t)(layer - 1) * 4 * HH * HH);
#pragma unroll
      for (int jj = 0; jj < JPW; ++jj) {
#pragma unroll
        for (int g = 0; g < 4; ++g) {
          const int row = g * HH + j0 + jj;
#pragma unroll
          for (int m = 0; m < 8; ++m)
            whh[jj][g][m] = WHH[(size_t)row * HH + m * 64 + lane];
        }
      }
      if (layer == 0) {
#pragma unroll
        for (int jj = 0; jj < JPW; ++jj)
#pragma unroll
          for (int g = 0; g < 4; ++g)
            bias[jj][g] = b_ih0[g * HH + j0 + jj] + b_hh0[g * HH + j0 + jj];
      } else {
        const float* BIH = b_ih + (size_t)(layer - 1) * 4 * HH;
        const float* BHH = b_hh + (size_t)(layer - 1) * 4 * HH;
#pragma unroll
        for (int jj = 0; jj < JPW; ++jj)
#pragma unroll
          for (int g = 0; g < 4; ++g)
            bias[jj][g] = BIH[g * HH + j0 + jj] + BHH[g * HH + j0 + jj];
      }
#pragma unroll
      for (int jj = 0; jj < JPW; ++jj) {
#pragma unroll
        for (int g = 0; g < 4; ++g) {
#pragma unroll
          for (int m = 0; m < 8; ++m) asm volatile("" : "+v"(whh[jj][g][m]));
          asm volatile("" : "+v"(bias[jj][g]));
        }
      }
    }
    // wih -> LDS (all threads cooperate), layout [out16][g][k]
    {
      const float* WIH = (layer == 0) ? (const float*)0
                                      : (w_ih + (size_t)(layer - 1) * 4 * HH * HH);
      for (int f = tid; f < 16 * 4 * HH; f += 1024) {
        const int oo = f >> 11;          // /2048: output 0..15
        const int g = (f >> 9) & 3;
        const int k = f & 511;
        const int row = g * HH + slot * 16 + oo;
        float v;
        if (layer == 0) v = (k < II) ? w_ih0[(size_t)row * II + k] : 0.0f;
        else v = WIH[(size_t)row * HH + k];
        wihs[f] = v;
      }
    }
    // prime staging for step 0 into buf 0
    if (!is_comp) {
      const int k = tid - CW * 64;
      hbuf[0][k] = 0.0f;
      if (layer == 0) xbuf[0][k] = (k < II) ? x[k] : 0.0f;
      else xbuf[0][k] = poll_ring(prevring + 0 * HH + k, 1u);  // prev h_0, tag 1
    }
    __syncthreads();

    float c[JPW] = {0.0f, 0.0f};

    // ---- recurrence: specialized waves, dbuf, ONE sync per step ----
    for (int t = 0; t < TT; ++t) {
      const int ph = t & 1;
      if (is_comp) {
        float hp[8], xin[8];
#pragma unroll
        for (int m = 0; m < 8; ++m) {
          hp[m] = hbuf[ph][m * 64 + lane];
          xin[m] = xbuf[ph][m * 64 + lane];
        }
        float acc[JPW][4];
#pragma unroll
        for (int jj = 0; jj < JPW; ++jj)
#pragma unroll
          for (int g = 0; g < 4; ++g) acc[jj][g] = 0.0f;
#pragma unroll
        for (int m = 0; m < 8; ++m) {
          const float hv = hp[m];
#pragma unroll
          for (int jj = 0; jj < JPW; ++jj) {
            acc[jj][0] = fmaf(whh[jj][0][m], hv, acc[jj][0]);
            acc[jj][1] = fmaf(whh[jj][1][m], hv, acc[jj][1]);
            acc[jj][2] = fmaf(whh[jj][2][m], hv, acc[jj][2]);
            acc[jj][3] = fmaf(whh[jj][3][m], hv, acc[jj][3]);
          }
        }
#pragma unroll
        for (int m = 0; m < 8; ++m) {
          const float xv = xin[m];
          const int o = m * 64 + lane;
#pragma unroll
          for (int jj = 0; jj < JPW; ++jj) {
            const float* wb = wihs + (size_t)(wv * JPW + jj) * 4 * HH;
            acc[jj][0] = fmaf(wb[0 * HH + o], xv, acc[jj][0]);
            acc[jj][1] = fmaf(wb[1 * HH + o], xv, acc[jj][1]);
            acc[jj][2] = fmaf(wb[2 * HH + o], xv, acc[jj][2]);
            acc[jj][3] = fmaf(wb[3 * HH + o], xv, acc[jj][3]);
          }
        }
        float hout[JPW];
#pragma unroll
        for (int jj = 0; jj < JPW; ++jj) {
          float ai = wave_sum(acc[jj][0]);
          float af = wave_sum(acc[jj][1]);
          float ag = wave_sum(acc[jj][2]);
          float ao = wave_sum(acc[jj][3]);
          float gi = sigmoidf_(ai + bias[jj][0]);
          float gf = sigmoidf_(af + bias[jj][1]);
          float gg = tanhf(ag + bias[jj][2]);
          float go = sigmoidf_(ao + bias[jj][3]);
          c[jj] = gf * c[jj] + gi * gg;
          hout[jj] = go * tanhf(c[jj]);
        }
        if (lane == 0) {
          const int sl = t & (RING - 1);
          const u64 tg = ((u64)(u32)(t + 1)) << 32;
          st8(myring + (size_t)sl * HH + j0, tg | (u64)__float_as_uint(hout[0]));
          st8(myring + (size_t)sl * HH + j0 + 1, tg | (u64)__float_as_uint(hout[1]));
          if (is_last) {
            h4[(size_t)t * HH + j0] = hout[0];
            h4[(size_t)t * HH + j0 + 1] = hout[1];
            h4T[(size_t)j0 * TT + t] = hout[0];
            h4T[(size_t)(j0 + 1) * TT + t] = hout[1];
          }
        }
      } else {
        const int k = tid - CW * 64;
        if (t + 1 < TT) {
          const int ph1 = ph ^ 1;
          const int slo = t & (RING - 1);        // own h_t, tag t+1 (this window)
          const int slp = (t + 1) & (RING - 1);  // prev h_{t+1}, tag t+2
          if (layer == 0) {
            xbuf[ph1][k] = (k < II) ? x[(size_t)(t + 1) * II + k] : 0.0f;
            hbuf[ph1][k] = poll_ring(myring + (size_t)slo * HH + k, (u32)(t + 1));
          } else {
            float ro, rp;
            poll2(myring + (size_t)slo * HH + k, (u32)(t + 1),
                  prevring + (size_t)slp * HH + k, (u32)(t + 2), &ro, &rp);
            hbuf[ph1][k] = ro;
            xbuf[ph1][k] = rp;
          }
        }
        if (k == 0) {
          if (slot == 0 && (t & 3) == 0 && t > 0) st4(prog_l, (u32)t);
          if (layer < LL - 1 && t >= 64 && (t & 7) == 0) {
            long sp = 0;
            while (ld4(prog_lp1) < (u32)(t - 40) && ++sp < SPIN_LIMIT) {}
          }
        }
      }
      __syncthreads();  // the single per-step barrier
    }
  }

  grid_barrier(garr, ggen, 2u);

  // ---- phase A: scores[t] = tanh(h4[t] . w_lin + b_lin) ----
  {
    const int gw = b * 16 + wv;
    if (gw < TT) {
      const int t = gw;
      const float4* hp4 = (const float4*)(h4 + (size_t)t * HH + lane * 8);
      const float4* wl4 = (const float4*)(w_lin + lane * 8);
      float4 a = hp4[0], d = hp4[1], wa = wl4[0], wd = wl4[1];
      float acc = 0.0f;
      acc = fmaf(a.x, wa.x, acc); acc = fmaf(a.y, wa.y, acc);
      acc = fmaf(a.z, wa.z, acc); acc = fmaf(a.w, wa.w, acc);
      acc = fmaf(d.x, wd.x, acc); acc = fmaf(d.y, wd.y, acc);
      acc = fmaf(d.z, wd.z, acc); acc = fmaf(d.w, wd.w, acc);
      acc = wave_sum(acc);
      float sc = tanhf(acc + b_lin[0]);
      if (lane == 0) scores[t] = sc;
    }
  }
  grid_barrier(garr, ggen, 3u);

  // ---- phase B: softmax over time (block 0 only) ----
  if (b == 0) {
    float s0 = scores[tid];
    float s1 = scores[tid + 1024];
    float m = fmaxf(s0, s1);
    m = wave_max(m);
    if (lane == 0) sbuf[wv] = m;
    __syncthreads();
    if (tid == 0) {
      float M = sbuf[0];
      for (int k = 1; k < 16; ++k) M = fmaxf(M, sbuf[k]);
      sbuf[16] = M;
    }
    __syncthreads();
    float M = sbuf[16];
    float p0 = expf(s0 - M), p1 = expf(s1 - M);
    pbuf[tid] = p0;
    pbuf[tid + 1024] = p1;
    float ssum = wave_sum(p0 + p1);
    __syncthreads();
    if (lane == 0) sbuf[wv] = ssum;
    __syncthreads();
    if (tid == 0) {
      float S = 0.0f;
      for (int k = 0; k < 16; ++k) S += sbuf[k];
      red[0] = 1.0f / ((float)TT * S);
    }
  }
  grid_barrier(garr, ggen, 4u);

  // ---- phase C: out[j] = scale * sum_t p_t * h4T[j][t] ----
  {
    const int gw = b * 16 + wv;
    if (gw < HH) {
      const float scale = red[0];
      const float* hr = h4T + (size_t)gw * TT + lane * 32;
      const float* pr = pbuf + lane * 32;
      float acc = 0.0f;
#pragma unroll
      for (int m = 0; m < 32; ++m) acc = fmaf(hr[m], pr[m], acc);
      acc = wave_sum(acc);
      if (lane == 0) out[gw] = scale * acc;
    }
  }
}

extern "C" void kernel_launch(void* const* d_in, const int* in_sizes, int n_in,
                              void* d_out, int out_size, void* d_ws, size_t ws_size,
                              hipStream_t stream) {
  hipFuncSetAttribute((const void*)lstm_pipe,
                      hipFuncAttributeMaxDynamicSharedMemorySize, 131072);
  hipMemsetAsync(d_ws, 0, 4096, stream);  // zero sync/claim counters
  lstm_pipe<<<dim3(NBLK), dim3(1024), 131072, stream>>>(
      (const float*)d_in[0],
      (const float*)d_in[1], (const float*)d_in[2],
      (const float*)d_in[3], (const float*)d_in[4],
      (const float*)d_in[5], (const float*)d_in[6],
      (const float*)d_in[7], (const float*)d_in[8],
      (const float*)d_in[9], (const float*)d_in[10],
      (float*)d_out, (float*)d_ws);
}